// Round 4
// baseline (3087.593 us; speedup 1.0000x reference)
//
#include <hip/hip_runtime.h>
#include <math.h>

#define N_RES 768
#define DS 384
#define DP 128
#define DH 16
#define NH 12
#define PQ 4
#define PV 8
#define HC (NH*DH)              // 192
#define CATD (NH*(DP+DH+PV*4))  // 2112
#define BK 64
#define ZP 132                  // padded z row (floats) — R1-measured near-free banks

// workspace float offsets
#define WS_Q   0
#define WS_K   (WS_Q + N_RES*HC)
#define WS_V   (WS_K + N_RES*HC)
#define WS_QP  (WS_V + N_RES*HC)            // [N][12][4][3]
#define WS_KP  (WS_QP + N_RES*NH*PQ*3)
#define WS_VP  (WS_KP + N_RES*NH*PQ*3)      // [N][12][8][3]
#define WS_CAT (WS_VP + N_RES*NH*PV*3)      // [N][2112]

// ---------------- kernel 1: input projections + frame apply ----------------
__global__ __launch_bounds__(256) void k_proj(
    const float* __restrict__ s, const float* __restrict__ rot,
    const float* __restrict__ trans,
    const float* __restrict__ Wq, const float* __restrict__ bq,
    const float* __restrict__ Wkv, const float* __restrict__ bkv,
    const float* __restrict__ Wqp, const float* __restrict__ bqp,
    const float* __restrict__ Wkvp, const float* __restrict__ bkvp,
    float* __restrict__ ws)
{
    __shared__ float s_s[4][DS];
    __shared__ float rq[4][NH*PQ*3];
    __shared__ float rkv[4][NH*(PQ+PV)*3];
    const int t = threadIdx.x;
    const int n0 = blockIdx.x * 4;

    for (int idx = t; idx < 4 * DS; idx += 256)
        s_s[idx / DS][idx % DS] = s[(n0 + idx / DS) * DS + idx % DS];
    __syncthreads();

    // 1152 output columns: [Wq 192 | Wkv 384 | Wqp 144 | Wkvp 432]
    for (int j = t; j < 1152; j += 256) {
        const float* W; int col, nc; float bias;
        if (j < 192)      { W = Wq;   col = j;       nc = 192; bias = bq[col]; }
        else if (j < 576) { W = Wkv;  col = j - 192; nc = 384; bias = bkv[col]; }
        else if (j < 720) { W = Wqp;  col = j - 576; nc = 144; bias = bqp[col]; }
        else              { W = Wkvp; col = j - 720; nc = 432; bias = bkvp[col]; }
        float acc[4];
        #pragma unroll
        for (int r = 0; r < 4; r++) acc[r] = bias;
        for (int i = 0; i < DS; i++) {
            float w = W[i * nc + col];
            #pragma unroll
            for (int r = 0; r < 4; r++) acc[r] += s_s[r][i] * w;
        }
        if (j < 192) {
            #pragma unroll
            for (int r = 0; r < 4; r++) ws[WS_Q + (n0 + r) * HC + j] = acc[r];
        } else if (j < 576) {
            int jj = j - 192, h = jj / 32, dd = jj % 32;
            if (dd < 16) {
                #pragma unroll
                for (int r = 0; r < 4; r++) ws[WS_K + (n0 + r) * HC + h * 16 + dd] = acc[r];
            } else {
                #pragma unroll
                for (int r = 0; r < 4; r++) ws[WS_V + (n0 + r) * HC + h * 16 + dd - 16] = acc[r];
            }
        } else if (j < 720) {
            #pragma unroll
            for (int r = 0; r < 4; r++) rq[r][j - 576] = acc[r];
        } else {
            #pragma unroll
            for (int r = 0; r < 4; r++) rkv[r][j - 720] = acc[r];
        }
    }
    __syncthreads();

    // frame apply: 4 rows * (48 qp + 144 kvp) points
    for (int idx = t; idx < 4 * 192; idx += 256) {
        int r = idx / 192, pi = idx % 192;
        int n = n0 + r;
        float x, y, zc; float* dst;
        if (pi < 48) {
            x = rq[r][pi]; y = rq[r][48 + pi]; zc = rq[r][96 + pi];
            dst = ws + WS_QP + n * (NH * PQ * 3) + pi * 3;
        } else {
            int p2 = pi - 48;
            x = rkv[r][p2]; y = rkv[r][144 + p2]; zc = rkv[r][288 + p2];
            int h = p2 / 12, pp = p2 % 12;
            if (pp < 4) dst = ws + WS_KP + n * (NH * PQ * 3) + (h * PQ + pp) * 3;
            else        dst = ws + WS_VP + n * (NH * PV * 3) + (h * PV + pp - 4) * 3;
        }
        const float* R = rot + n * 9;
        const float* T = trans + n * 3;
        dst[0] = R[0] * x + R[1] * y + R[2] * zc + T[0];
        dst[1] = R[3] * x + R[4] * y + R[5] * zc + T[1];
        dst[2] = R[6] * x + R[7] * y + R[8] * zc + T[2];
    }
}

// ---------------- kernel 2: fused IPA attention, one block per q row ----------------
// 256 threads = 4 waves; wave w owns heads 3w..3w+2. Single padded z LDS buffer,
// synchronous staging (loads issued pre-barrier; regs dead during compute).
__global__ __launch_bounds__(256, 3) void k_attn(
    const float* __restrict__ zg, const float* __restrict__ mask,
    const float* __restrict__ rot, const float* __restrict__ trans,
    const float* __restrict__ Wb, const float* __restrict__ bb,
    const float* __restrict__ hweights,
    float* __restrict__ ws)
{
    __shared__ float z_s[BK * ZP];        // 33.8 KB, pad-132
    __shared__ float Wb_s[NH][DP];        // 6 KB
    __shared__ float p_s[NH][68];
    __shared__ float q_s[HC];
    __shared__ float qpts_s[NH * PQ * 3];
    __shared__ float opts_s[NH * PV * 3];
    __shared__ float r_s[NH];
    __shared__ float inv_s[NH];
    __shared__ float rot_s[9], trans_s[3];

    const int t = threadIdx.x;
    const int lane = t & 63;
    const int w = t >> 6;        // wave 0..3
    const int h0 = 3 * w;        // this wave's heads: h0..h0+2
    const int q = blockIdx.x;
    const float* zq = zg + (size_t)q * N_RES * DP;

    for (int i = t; i < HC; i += 256) q_s[i] = ws[WS_Q + q * HC + i];
    for (int i = t; i < NH * PQ * 3; i += 256) qpts_s[i] = ws[WS_QP + q * NH * PQ * 3 + i];
    for (int i = t; i < NH * DP; i += 256) {     // transpose Wb (128,12) -> [h][c]
        int c = i / NH, h = i % NH;
        Wb_s[h][c] = Wb[i];
    }
    if (t < 9) rot_s[t] = rot[q * 9 + t];
    if (t < 3) trans_s[t] = trans[q * 3 + t];

    float hw[3], bbv[3];
    #pragma unroll
    for (int hl = 0; hl < 3; hl++) {
        float x = hweights[h0 + hl];
        hw[hl] = log1pf(expf(x)) * 0.1360827635f;   // softplus * sqrt(1/54)
        bbv[hl] = bb[h0 + hl];
    }

    float m_run[3], ssum[3];
    float acc_z[3][2];
    #pragma unroll
    for (int hl = 0; hl < 3; hl++) {
        m_run[hl] = -1e30f; ssum[hl] = 0.f;
        acc_z[hl][0] = 0.f; acc_z[hl][1] = 0.f;
    }
    float acc_o = 0.f, acc_p0 = 0.f, acc_p1 = 0.f;

    const bool act_o = (lane < 48);
    const int h_o = h0 + (act_o ? (lane >> 4) : 0);   // o: flat = 48w + lane (lane<48)
    const int h_pA = h0 + lane / 24;                  // o_pts: flat = 72w + lane
    const bool act_p1 = (lane < 8);                   // flat = 72w + 64 + lane (head h0+2)

    for (int kb = 0; kb < N_RES; kb += BK) {
        // issue staging loads pre-barrier (overlap other waves' compute tail)
        float4 zr[8];
        {
            const float4* src = (const float4*)(zq + (size_t)kb * DP);
            #pragma unroll
            for (int i = 0; i < 8; i++) zr[i] = src[i * 256 + t];
        }
        __syncthreads();   // all waves done reading previous tile's z_s / p_s
        #pragma unroll
        for (int i = 0; i < 8; i++) {
            int idx = i * 256 + t;
            *(float4*)&z_s[(idx >> 5) * ZP + (idx & 31) * 4] = zr[i];
        }
        __syncthreads();   // tile staged

        // ---- logits for k = kb + lane, 3 heads ----
        const int kk = kb + lane;
        float logit[3];
        {
            float bacc[3] = {0.f, 0.f, 0.f};
            for (int c4 = 0; c4 < 32; c4++) {
                float4 z4 = *(const float4*)&z_s[lane * ZP + c4 * 4];
                #pragma unroll
                for (int hl = 0; hl < 3; hl++) {
                    float4 w4 = *(const float4*)&Wb_s[h0 + hl][c4 * 4];
                    bacc[hl] += z4.x * w4.x + z4.y * w4.y + z4.z * w4.z + z4.w * w4.w;
                }
            }
            const float* krow = ws + WS_K + (size_t)kk * HC;
            const float* kprow = ws + WS_KP + (size_t)kk * NH * PQ * 3;
            float mval = mask[q * N_RES + kk];
            #pragma unroll
            for (int hl = 0; hl < 3; hl++) {
                int gh = h0 + hl;
                float qk = 0.f;
                #pragma unroll
                for (int d4 = 0; d4 < 4; d4++) {
                    float4 q4 = *(const float4*)&q_s[gh * 16 + d4 * 4];
                    float4 k4 = *(const float4*)&krow[gh * 16 + d4 * 4];
                    qk += q4.x * k4.x + q4.y * k4.y + q4.z * k4.z + q4.w * k4.w;
                }
                float d2 = 0.f;
                #pragma unroll
                for (int p4i = 0; p4i < 3; p4i++) {
                    float4 a = *(const float4*)&qpts_s[gh * 12 + p4i * 4];
                    float4 b = *(const float4*)&kprow[gh * 12 + p4i * 4];
                    float dx = a.x - b.x, dy = a.y - b.y, dz = a.z - b.z, dw = a.w - b.w;
                    d2 += dx * dx + dy * dy + dz * dz + dw * dw;
                }
                logit[hl] = qk * 0.1443375673f + (bacc[hl] + bbv[hl]) * 0.5773502692f
                            + mval - 0.5f * hw[hl] * d2;
            }
        }

        // ---- online softmax (per head, 64-lane reduce; all wave-local) ----
        float rloc[3];
        #pragma unroll
        for (int hl = 0; hl < 3; hl++) {
            float lm = logit[hl];
            #pragma unroll
            for (int off = 32; off; off >>= 1) lm = fmaxf(lm, __shfl_xor(lm, off));
            float m_new = fmaxf(m_run[hl], lm);
            float rr = __expf(m_run[hl] - m_new);
            float p = __expf(logit[hl] - m_new);
            ssum[hl] = ssum[hl] * rr + p;
            p_s[h0 + hl][lane] = p;
            if (lane == 0) r_s[h0 + hl] = rr;
            rloc[hl] = rr;
            m_run[hl] = m_new;
        }
        // no barrier: p_s/r_s producers and consumers are the same wave

        // ---- o_pair from staged z ----
        #pragma unroll
        for (int hl = 0; hl < 3; hl++) {
            acc_z[hl][0] *= rloc[hl];
            acc_z[hl][1] *= rloc[hl];
        }
        #pragma unroll 4
        for (int j = 0; j < BK; j++) {
            float z0 = z_s[j * ZP + lane];
            float z1 = z_s[j * ZP + 64 + lane];
            #pragma unroll
            for (int hl = 0; hl < 3; hl++) {
                float pv = p_s[h0 + hl][j];
                acc_z[hl][0] += pv * z0;
                acc_z[hl][1] += pv * z1;
            }
        }

        // ---- accumulate o ----
        if (act_o) {
            acc_o *= r_s[h_o];
            const float* vbase = ws + WS_V + (size_t)kb * HC + w * 48 + lane;
            #pragma unroll 8
            for (int j = 0; j < BK; j++) {
                acc_o += p_s[h_o][j] * vbase[(size_t)j * HC];
            }
        }
        // ---- accumulate o_pts (global frame) ----
        {
            acc_p0 *= r_s[h_pA];
            if (act_p1) acc_p1 *= r_s[h0 + 2];
            const float* vpb = ws + WS_VP + (size_t)kb * (NH * PV * 3) + w * 72;
            #pragma unroll 8
            for (int j = 0; j < BK; j++) {
                const float* vr = vpb + (size_t)j * (NH * PV * 3);
                acc_p0 += p_s[h_pA][j] * vr[lane];
                if (act_p1) acc_p1 += p_s[h0 + 2][j] * vr[64 + lane];
            }
        }
    }

    // ---- final: denominators ----
    float inv[3];
    #pragma unroll
    for (int hl = 0; hl < 3; hl++) {
        float sv = ssum[hl];
        #pragma unroll
        for (int off = 32; off; off >>= 1) sv += __shfl_xor(sv, off);
        inv[hl] = 1.f / sv;
        if (lane == 0) inv_s[h0 + hl] = inv[hl];
    }

    float* cat = ws + WS_CAT + (size_t)q * CATD;
    // o
    if (act_o) cat[w * 48 + lane] = acc_o * inv_s[h_o];
    // o_pts normalized, global frame -> LDS for cross-wave gather
    opts_s[w * 72 + lane] = acc_p0 * inv_s[h_pA];
    if (act_p1) opts_s[w * 72 + 64 + lane] = acc_p1 * inv_s[h0 + 2];
    // o_pair
    #pragma unroll
    for (int hl = 0; hl < 3; hl++) {
        int gh = h0 + hl;
        cat[576 + gh * 128 + lane] = acc_z[hl][0] * inv[hl];
        cat[576 + gh * 128 + 64 + lane] = acc_z[hl][1] * inv[hl];
    }
    __syncthreads();   // opts_s crosses waves below

    // inverse frame + norm: t<96 -> (head, point)
    if (t < 96) {
        int gh = t >> 3, p = t & 7;
        float gx = opts_s[gh * 24 + p * 3 + 0] - trans_s[0];
        float gy = opts_s[gh * 24 + p * 3 + 1] - trans_s[1];
        float gz = opts_s[gh * 24 + p * 3 + 2] - trans_s[2];
        float lx = rot_s[0] * gx + rot_s[3] * gy + rot_s[6] * gz;
        float ly = rot_s[1] * gx + rot_s[4] * gy + rot_s[7] * gz;
        float lz = rot_s[2] * gx + rot_s[5] * gy + rot_s[8] * gz;
        cat[192 + t] = lx;
        cat[288 + t] = ly;
        cat[384 + t] = lz;
        cat[480 + t] = sqrtf(lx * lx + ly * ly + lz * lz + 1e-8f);
    }
}

// ---------------- kernel 3: cat @ Wout + bout ----------------
__global__ __launch_bounds__(384) void k_out(
    const float* __restrict__ ws, const float* __restrict__ Wout,
    const float* __restrict__ bout, float* __restrict__ out)
{
    __shared__ float cat_s[4][192];
    const int t = threadIdx.x;
    const int n0 = blockIdx.x * 4;
    float acc[4];
    #pragma unroll
    for (int r = 0; r < 4; r++) acc[r] = 0.f;
    for (int c0 = 0; c0 < CATD; c0 += 192) {
        __syncthreads();
        for (int idx = t; idx < 4 * 192; idx += 384)
            cat_s[idx / 192][idx % 192] =
                ws[WS_CAT + (size_t)(n0 + idx / 192) * CATD + c0 + idx % 192];
        __syncthreads();
        for (int i = 0; i < 192; i++) {
            float wv = Wout[(size_t)(c0 + i) * DS + t];
            #pragma unroll
            for (int r = 0; r < 4; r++) acc[r] += cat_s[r][i] * wv;
        }
    }
    float b = bout[t];
    #pragma unroll
    for (int r = 0; r < 4; r++) out[(size_t)(n0 + r) * DS + t] = acc[r] + b;
}

extern "C" void kernel_launch(void* const* d_in, const int* in_sizes, int n_in,
                              void* d_out, int out_size, void* d_ws, size_t ws_size,
                              hipStream_t stream)
{
    const float* s     = (const float*)d_in[0];
    const float* z     = (const float*)d_in[1];
    const float* mask  = (const float*)d_in[2];
    const float* rot   = (const float*)d_in[3];
    const float* trans = (const float*)d_in[4];
    const float* Wq    = (const float*)d_in[5];
    const float* bq    = (const float*)d_in[6];
    const float* Wkv   = (const float*)d_in[7];
    const float* bkv   = (const float*)d_in[8];
    const float* Wqp   = (const float*)d_in[9];
    const float* bqp   = (const float*)d_in[10];
    const float* Wkvp  = (const float*)d_in[11];
    const float* bkvp  = (const float*)d_in[12];
    const float* Wb    = (const float*)d_in[13];
    const float* bb    = (const float*)d_in[14];
    const float* hwt   = (const float*)d_in[15];
    const float* Wout  = (const float*)d_in[16];
    const float* bout  = (const float*)d_in[17];
    float* ws  = (float*)d_ws;
    float* out = (float*)d_out;

    hipLaunchKernelGGL(k_proj, dim3(192), dim3(256), 0, stream,
                       s, rot, trans, Wq, bq, Wkv, bkv, Wqp, bqp, Wkvp, bkvp, ws);
    hipLaunchKernelGGL(k_attn, dim3(768), dim3(256), 0, stream,
                       z, mask, rot, trans, Wb, bb, hwt, ws);
    hipLaunchKernelGGL(k_out, dim3(192), dim3(384), 0, stream,
                       ws, Wout, bout, out);
}

// Round 5
// 1861.779 us; speedup vs baseline: 1.6584x; 1.6584x over previous
//
#include <hip/hip_runtime.h>
#include <math.h>

#define N_RES 768
#define DS 384
#define DP 128
#define DH 16
#define NH 12
#define PQ 4
#define PV 8
#define HC (NH*DH)              // 192
#define CATD (NH*(DP+DH+PV*4))  // 2112
#define BK 64
#define ZP 132                  // padded z row (floats) — R1-measured near-free banks

// workspace float offsets
#define WS_Q   0
#define WS_K   (WS_Q + N_RES*HC)
#define WS_V   (WS_K + N_RES*HC)
#define WS_QP  (WS_V + N_RES*HC)            // [N][12][4][3]
#define WS_KP  (WS_QP + N_RES*NH*PQ*3)
#define WS_VP  (WS_KP + N_RES*NH*PQ*3)      // [N][12][8][3]
#define WS_CAT (WS_VP + N_RES*NH*PV*3)      // [N][2112]

// ---------------- kernel 1: input projections + frame apply ----------------
__global__ __launch_bounds__(256) void k_proj(
    const float* __restrict__ s, const float* __restrict__ rot,
    const float* __restrict__ trans,
    const float* __restrict__ Wq, const float* __restrict__ bq,
    const float* __restrict__ Wkv, const float* __restrict__ bkv,
    const float* __restrict__ Wqp, const float* __restrict__ bqp,
    const float* __restrict__ Wkvp, const float* __restrict__ bkvp,
    float* __restrict__ ws)
{
    __shared__ float s_s[4][DS];
    __shared__ float rq[4][NH*PQ*3];
    __shared__ float rkv[4][NH*(PQ+PV)*3];
    const int t = threadIdx.x;
    const int n0 = blockIdx.x * 4;

    for (int idx = t; idx < 4 * DS; idx += 256)
        s_s[idx / DS][idx % DS] = s[(n0 + idx / DS) * DS + idx % DS];
    __syncthreads();

    // 1152 output columns: [Wq 192 | Wkv 384 | Wqp 144 | Wkvp 432]
    for (int j = t; j < 1152; j += 256) {
        const float* W; int col, nc; float bias;
        if (j < 192)      { W = Wq;   col = j;       nc = 192; bias = bq[col]; }
        else if (j < 576) { W = Wkv;  col = j - 192; nc = 384; bias = bkv[col]; }
        else if (j < 720) { W = Wqp;  col = j - 576; nc = 144; bias = bqp[col]; }
        else              { W = Wkvp; col = j - 720; nc = 432; bias = bkvp[col]; }
        float acc[4];
        #pragma unroll
        for (int r = 0; r < 4; r++) acc[r] = bias;
        for (int i = 0; i < DS; i++) {
            float w = W[i * nc + col];
            #pragma unroll
            for (int r = 0; r < 4; r++) acc[r] += s_s[r][i] * w;
        }
        if (j < 192) {
            #pragma unroll
            for (int r = 0; r < 4; r++) ws[WS_Q + (n0 + r) * HC + j] = acc[r];
        } else if (j < 576) {
            int jj = j - 192, h = jj / 32, dd = jj % 32;
            if (dd < 16) {
                #pragma unroll
                for (int r = 0; r < 4; r++) ws[WS_K + (n0 + r) * HC + h * 16 + dd] = acc[r];
            } else {
                #pragma unroll
                for (int r = 0; r < 4; r++) ws[WS_V + (n0 + r) * HC + h * 16 + dd - 16] = acc[r];
            }
        } else if (j < 720) {
            #pragma unroll
            for (int r = 0; r < 4; r++) rq[r][j - 576] = acc[r];
        } else {
            #pragma unroll
            for (int r = 0; r < 4; r++) rkv[r][j - 720] = acc[r];
        }
    }
    __syncthreads();

    // frame apply: 4 rows * (48 qp + 144 kvp) points
    for (int idx = t; idx < 4 * 192; idx += 256) {
        int r = idx / 192, pi = idx % 192;
        int n = n0 + r;
        float x, y, zc; float* dst;
        if (pi < 48) {
            x = rq[r][pi]; y = rq[r][48 + pi]; zc = rq[r][96 + pi];
            dst = ws + WS_QP + n * (NH * PQ * 3) + pi * 3;
        } else {
            int p2 = pi - 48;
            x = rkv[r][p2]; y = rkv[r][144 + p2]; zc = rkv[r][288 + p2];
            int h = p2 / 12, pp = p2 % 12;
            if (pp < 4) dst = ws + WS_KP + n * (NH * PQ * 3) + (h * PQ + pp) * 3;
            else        dst = ws + WS_VP + n * (NH * PV * 3) + (h * PV + pp - 4) * 3;
        }
        const float* R = rot + n * 9;
        const float* T = trans + n * 3;
        dst[0] = R[0] * x + R[1] * y + R[2] * zc + T[0];
        dst[1] = R[3] * x + R[4] * y + R[5] * zc + T[1];
        dst[2] = R[6] * x + R[7] * y + R[8] * zc + T[2];
    }
}

// ---------------- kernel 2: fused IPA attention, one block per q row ----------------
// 256 threads = 4 waves; wave w owns heads 3w..3w+2. Single padded z LDS buffer,
// synchronous staging (loads issued pre-barrier; regs dead during compute).
// NO min-waves clamp: R4's (256,3) forced VGPR=84 -> 6.6 GB scratch spill traffic.
__global__ __launch_bounds__(256) void k_attn(
    const float* __restrict__ zg, const float* __restrict__ mask,
    const float* __restrict__ rot, const float* __restrict__ trans,
    const float* __restrict__ Wb, const float* __restrict__ bb,
    const float* __restrict__ hweights,
    float* __restrict__ ws)
{
    __shared__ float z_s[BK * ZP];        // 33.8 KB, pad-132
    __shared__ float Wb_s[NH][DP];        // 6 KB
    __shared__ float p_s[NH][68];
    __shared__ float q_s[HC];
    __shared__ float qpts_s[NH * PQ * 3];
    __shared__ float opts_s[NH * PV * 3];
    __shared__ float r_s[NH];
    __shared__ float inv_s[NH];
    __shared__ float rot_s[9], trans_s[3];

    const int t = threadIdx.x;
    const int lane = t & 63;
    const int w = t >> 6;        // wave 0..3
    const int h0 = 3 * w;        // this wave's heads: h0..h0+2
    const int q = blockIdx.x;
    const float* zq = zg + (size_t)q * N_RES * DP;

    for (int i = t; i < HC; i += 256) q_s[i] = ws[WS_Q + q * HC + i];
    for (int i = t; i < NH * PQ * 3; i += 256) qpts_s[i] = ws[WS_QP + q * NH * PQ * 3 + i];
    for (int i = t; i < NH * DP; i += 256) {     // transpose Wb (128,12) -> [h][c]
        int c = i / NH, h = i % NH;
        Wb_s[h][c] = Wb[i];
    }
    if (t < 9) rot_s[t] = rot[q * 9 + t];
    if (t < 3) trans_s[t] = trans[q * 3 + t];

    float hw[3], bbv[3];
    #pragma unroll
    for (int hl = 0; hl < 3; hl++) {
        float x = hweights[h0 + hl];
        hw[hl] = log1pf(expf(x)) * 0.1360827635f;   // softplus * sqrt(1/54)
        bbv[hl] = bb[h0 + hl];
    }

    float m_run[3], ssum[3];
    float acc_z[3][2];
    #pragma unroll
    for (int hl = 0; hl < 3; hl++) {
        m_run[hl] = -1e30f; ssum[hl] = 0.f;
        acc_z[hl][0] = 0.f; acc_z[hl][1] = 0.f;
    }
    float acc_o = 0.f, acc_p0 = 0.f, acc_p1 = 0.f;

    const bool act_o = (lane < 48);
    const int h_o = h0 + (act_o ? (lane >> 4) : 0);   // o: flat = 48w + lane (lane<48)
    const int h_pA = h0 + lane / 24;                  // o_pts: flat = 72w + lane
    const bool act_p1 = (lane < 8);                   // flat = 72w + 64 + lane (head h0+2)

    for (int kb = 0; kb < N_RES; kb += BK) {
        // issue staging loads pre-barrier (overlap other waves' compute tail)
        float4 zr[8];
        {
            const float4* src = (const float4*)(zq + (size_t)kb * DP);
            #pragma unroll
            for (int i = 0; i < 8; i++) zr[i] = src[i * 256 + t];
        }
        __syncthreads();   // all waves done reading previous tile's z_s / p_s
        #pragma unroll
        for (int i = 0; i < 8; i++) {
            int idx = i * 256 + t;
            *(float4*)&z_s[(idx >> 5) * ZP + (idx & 31) * 4] = zr[i];
        }
        __syncthreads();   // tile staged

        // ---- logits for k = kb + lane, 3 heads ----
        const int kk = kb + lane;
        float logit[3];
        {
            float bacc[3] = {0.f, 0.f, 0.f};
            for (int c4 = 0; c4 < 32; c4++) {
                float4 z4 = *(const float4*)&z_s[lane * ZP + c4 * 4];
                #pragma unroll
                for (int hl = 0; hl < 3; hl++) {
                    float4 w4 = *(const float4*)&Wb_s[h0 + hl][c4 * 4];
                    bacc[hl] += z4.x * w4.x + z4.y * w4.y + z4.z * w4.z + z4.w * w4.w;
                }
            }
            const float* krow = ws + WS_K + (size_t)kk * HC;
            const float* kprow = ws + WS_KP + (size_t)kk * NH * PQ * 3;
            float mval = mask[q * N_RES + kk];
            #pragma unroll
            for (int hl = 0; hl < 3; hl++) {
                int gh = h0 + hl;
                float qk = 0.f;
                #pragma unroll
                for (int d4 = 0; d4 < 4; d4++) {
                    float4 q4 = *(const float4*)&q_s[gh * 16 + d4 * 4];
                    float4 k4 = *(const float4*)&krow[gh * 16 + d4 * 4];
                    qk += q4.x * k4.x + q4.y * k4.y + q4.z * k4.z + q4.w * k4.w;
                }
                float d2 = 0.f;
                #pragma unroll
                for (int p4i = 0; p4i < 3; p4i++) {
                    float4 a = *(const float4*)&qpts_s[gh * 12 + p4i * 4];
                    float4 b = *(const float4*)&kprow[gh * 12 + p4i * 4];
                    float dx = a.x - b.x, dy = a.y - b.y, dz = a.z - b.z, dw = a.w - b.w;
                    d2 += dx * dx + dy * dy + dz * dz + dw * dw;
                }
                logit[hl] = qk * 0.1443375673f + (bacc[hl] + bbv[hl]) * 0.5773502692f
                            + mval - 0.5f * hw[hl] * d2;
            }
        }

        // ---- online softmax (per head, 64-lane reduce; all wave-local) ----
        float rloc[3];
        #pragma unroll
        for (int hl = 0; hl < 3; hl++) {
            float lm = logit[hl];
            #pragma unroll
            for (int off = 32; off; off >>= 1) lm = fmaxf(lm, __shfl_xor(lm, off));
            float m_new = fmaxf(m_run[hl], lm);
            float rr = __expf(m_run[hl] - m_new);
            float p = __expf(logit[hl] - m_new);
            ssum[hl] = ssum[hl] * rr + p;
            p_s[h0 + hl][lane] = p;
            if (lane == 0) r_s[h0 + hl] = rr;
            rloc[hl] = rr;
            m_run[hl] = m_new;
        }
        // no barrier: p_s/r_s producers and consumers are the same wave

        // ---- o_pair from staged z ----
        #pragma unroll
        for (int hl = 0; hl < 3; hl++) {
            acc_z[hl][0] *= rloc[hl];
            acc_z[hl][1] *= rloc[hl];
        }
        #pragma unroll 4
        for (int j = 0; j < BK; j++) {
            float z0 = z_s[j * ZP + lane];
            float z1 = z_s[j * ZP + 64 + lane];
            #pragma unroll
            for (int hl = 0; hl < 3; hl++) {
                float pv = p_s[h0 + hl][j];
                acc_z[hl][0] += pv * z0;
                acc_z[hl][1] += pv * z1;
            }
        }

        // ---- accumulate o ----
        if (act_o) {
            acc_o *= r_s[h_o];
            const float* vbase = ws + WS_V + (size_t)kb * HC + w * 48 + lane;
            #pragma unroll 8
            for (int j = 0; j < BK; j++) {
                acc_o += p_s[h_o][j] * vbase[(size_t)j * HC];
            }
        }
        // ---- accumulate o_pts (global frame) ----
        {
            acc_p0 *= r_s[h_pA];
            if (act_p1) acc_p1 *= r_s[h0 + 2];
            const float* vpb = ws + WS_VP + (size_t)kb * (NH * PV * 3) + w * 72;
            #pragma unroll 8
            for (int j = 0; j < BK; j++) {
                const float* vr = vpb + (size_t)j * (NH * PV * 3);
                acc_p0 += p_s[h_pA][j] * vr[lane];
                if (act_p1) acc_p1 += p_s[h0 + 2][j] * vr[64 + lane];
            }
        }
    }

    // ---- final: denominators ----
    float inv[3];
    #pragma unroll
    for (int hl = 0; hl < 3; hl++) {
        float sv = ssum[hl];
        #pragma unroll
        for (int off = 32; off; off >>= 1) sv += __shfl_xor(sv, off);
        inv[hl] = 1.f / sv;
        if (lane == 0) inv_s[h0 + hl] = inv[hl];
    }

    float* cat = ws + WS_CAT + (size_t)q * CATD;
    // o
    if (act_o) cat[w * 48 + lane] = acc_o * inv_s[h_o];
    // o_pts normalized, global frame -> LDS for cross-wave gather
    opts_s[w * 72 + lane] = acc_p0 * inv_s[h_pA];
    if (act_p1) opts_s[w * 72 + 64 + lane] = acc_p1 * inv_s[h0 + 2];
    // o_pair
    #pragma unroll
    for (int hl = 0; hl < 3; hl++) {
        int gh = h0 + hl;
        cat[576 + gh * 128 + lane] = acc_z[hl][0] * inv[hl];
        cat[576 + gh * 128 + 64 + lane] = acc_z[hl][1] * inv[hl];
    }
    __syncthreads();   // opts_s crosses waves below

    // inverse frame + norm: t<96 -> (head, point)
    if (t < 96) {
        int gh = t >> 3, p = t & 7;
        float gx = opts_s[gh * 24 + p * 3 + 0] - trans_s[0];
        float gy = opts_s[gh * 24 + p * 3 + 1] - trans_s[1];
        float gz = opts_s[gh * 24 + p * 3 + 2] - trans_s[2];
        float lx = rot_s[0] * gx + rot_s[3] * gy + rot_s[6] * gz;
        float ly = rot_s[1] * gx + rot_s[4] * gy + rot_s[7] * gz;
        float lz = rot_s[2] * gx + rot_s[5] * gy + rot_s[8] * gz;
        cat[192 + t] = lx;
        cat[288 + t] = ly;
        cat[384 + t] = lz;
        cat[480 + t] = sqrtf(lx * lx + ly * ly + lz * lz + 1e-8f);
    }
}

// ---------------- kernel 3: cat @ Wout + bout ----------------
__global__ __launch_bounds__(384) void k_out(
    const float* __restrict__ ws, const float* __restrict__ Wout,
    const float* __restrict__ bout, float* __restrict__ out)
{
    __shared__ float cat_s[4][192];
    const int t = threadIdx.x;
    const int n0 = blockIdx.x * 4;
    float acc[4];
    #pragma unroll
    for (int r = 0; r < 4; r++) acc[r] = 0.f;
    for (int c0 = 0; c0 < CATD; c0 += 192) {
        __syncthreads();
        for (int idx = t; idx < 4 * 192; idx += 384)
            cat_s[idx / 192][idx % 192] =
                ws[WS_CAT + (size_t)(n0 + idx / 192) * CATD + c0 + idx % 192];
        __syncthreads();
        for (int i = 0; i < 192; i++) {
            float wv = Wout[(size_t)(c0 + i) * DS + t];
            #pragma unroll
            for (int r = 0; r < 4; r++) acc[r] += cat_s[r][i] * wv;
        }
    }
    float b = bout[t];
    #pragma unroll
    for (int r = 0; r < 4; r++) out[(size_t)(n0 + r) * DS + t] = acc[r] + b;
}

extern "C" void kernel_launch(void* const* d_in, const int* in_sizes, int n_in,
                              void* d_out, int out_size, void* d_ws, size_t ws_size,
                              hipStream_t stream)
{
    const float* s     = (const float*)d_in[0];
    const float* z     = (const float*)d_in[1];
    const float* mask  = (const float*)d_in[2];
    const float* rot   = (const float*)d_in[3];
    const float* trans = (const float*)d_in[4];
    const float* Wq    = (const float*)d_in[5];
    const float* bq    = (const float*)d_in[6];
    const float* Wkv   = (const float*)d_in[7];
    const float* bkv   = (const float*)d_in[8];
    const float* Wqp   = (const float*)d_in[9];
    const float* bqp   = (const float*)d_in[10];
    const float* Wkvp  = (const float*)d_in[11];
    const float* bkvp  = (const float*)d_in[12];
    const float* Wb    = (const float*)d_in[13];
    const float* bb    = (const float*)d_in[14];
    const float* hwt   = (const float*)d_in[15];
    const float* Wout  = (const float*)d_in[16];
    const float* bout  = (const float*)d_in[17];
    float* ws  = (float*)d_ws;
    float* out = (float*)d_out;

    hipLaunchKernelGGL(k_proj, dim3(192), dim3(256), 0, stream,
                       s, rot, trans, Wq, bq, Wkv, bkv, Wqp, bqp, Wkvp, bkvp, ws);
    hipLaunchKernelGGL(k_attn, dim3(768), dim3(256), 0, stream,
                       z, mask, rot, trans, Wb, bb, hwt, ws);
    hipLaunchKernelGGL(k_out, dim3(192), dim3(384), 0, stream,
                       ws, Wout, bout, out);
}

// Round 6
// 1408.619 us; speedup vs baseline: 2.1919x; 1.3217x over previous
//
#include <hip/hip_runtime.h>
#include <hip/hip_fp16.h>
#include <math.h>

#define N_RES 768
#define DS 384
#define DP 128
#define DH 16
#define NH 12
#define PQ 4
#define PV 8
#define HC (NH*DH)              // 192
#define CATD (NH*(DP+DH+PV*4))  // 2112
#define BK 64

// ws float offsets
#define WS_Q    0                              // [768][192]
#define WS_KT   (WS_Q   + N_RES*HC)            // [12][16][768]  K transposed
#define WS_V    (WS_KT  + NH*DH*N_RES)         // [768][192]
#define WS_QP   (WS_V   + N_RES*HC)            // [768][12][4][3] framed q pts
#define WS_KPT  (WS_QP  + N_RES*NH*PQ*3)       // [12][12][768]  framed k pts transposed
#define WS_VP   (WS_KPT + NH*PQ*3*N_RES)       // [768][12][8][3]
#define WS_KPSQ (WS_VP  + N_RES*NH*PV*3)       // [768][12]  sum_p |kp|^2
#define WS_BASE (WS_KPSQ+ N_RES*NH)            // fp16 [768][12][768] logit base
#define BASE_FLOATS (N_RES*NH*N_RES/2)
#define WS_CAT  (WS_BASE+ BASE_FLOATS)         // [768][2112]

// ---------------- kernel 1: input projections + frame apply ----------------
__global__ __launch_bounds__(256) void k_proj(
    const float* __restrict__ s, const float* __restrict__ rot,
    const float* __restrict__ trans,
    const float* __restrict__ Wq, const float* __restrict__ bq,
    const float* __restrict__ Wkv, const float* __restrict__ bkv,
    const float* __restrict__ Wqp, const float* __restrict__ bqp,
    const float* __restrict__ Wkvp, const float* __restrict__ bkvp,
    float* __restrict__ ws)
{
    __shared__ float s_s[8][DS];
    __shared__ float rq[8][NH*PQ*3];
    __shared__ float rkv[8][NH*(PQ+PV)*3];
    __shared__ float kpsq_s[8][NH];
    const int t = threadIdx.x;
    const int n0 = blockIdx.x * 8;

    for (int idx = t; idx < 8 * DS; idx += 256)
        s_s[idx / DS][idx % DS] = s[(n0 + idx / DS) * DS + idx % DS];
    if (t < 96) kpsq_s[t / 12][t % 12] = 0.f;
    __syncthreads();

    // 1152 output columns: [Wq 192 | Wkv 384 | Wqp 144 | Wkvp 432]
    for (int j = t; j < 1152; j += 256) {
        const float* W; int col, nc; float bias;
        if (j < 192)      { W = Wq;   col = j;       nc = 192; bias = bq[col]; }
        else if (j < 576) { W = Wkv;  col = j - 192; nc = 384; bias = bkv[col]; }
        else if (j < 720) { W = Wqp;  col = j - 576; nc = 144; bias = bqp[col]; }
        else              { W = Wkvp; col = j - 720; nc = 432; bias = bkvp[col]; }
        float acc[8];
        #pragma unroll
        for (int r = 0; r < 8; r++) acc[r] = bias;
        for (int i = 0; i < DS; i++) {
            float w = W[i * nc + col];
            #pragma unroll
            for (int r = 0; r < 8; r++) acc[r] += s_s[r][i] * w;
        }
        if (j < 192) {
            #pragma unroll
            for (int r = 0; r < 8; r++) ws[WS_Q + (size_t)(n0 + r) * HC + j] = acc[r];
        } else if (j < 576) {
            int jj = j - 192, h = jj / 32, dd = jj % 32;
            if (dd < 16) {  // K -> transposed [h][d][k]
                #pragma unroll
                for (int r = 0; r < 8; r++)
                    ws[WS_KT + (size_t)(h * DH + dd) * N_RES + (n0 + r)] = acc[r];
            } else {
                #pragma unroll
                for (int r = 0; r < 8; r++)
                    ws[WS_V + (size_t)(n0 + r) * HC + h * 16 + dd - 16] = acc[r];
            }
        } else if (j < 720) {
            #pragma unroll
            for (int r = 0; r < 8; r++) rq[r][j - 576] = acc[r];
        } else {
            #pragma unroll
            for (int r = 0; r < 8; r++) rkv[r][j - 720] = acc[r];
        }
    }
    __syncthreads();

    // frame apply: 8 rows * (48 qp + 144 kvp) points
    for (int idx = t; idx < 8 * 192; idx += 256) {
        int r = idx / 192, pi = idx % 192;
        int n = n0 + r;
        const float* R = rot + n * 9;
        const float* T = trans + n * 3;
        if (pi < 48) {
            float x = rq[r][pi], y = rq[r][48 + pi], zc = rq[r][96 + pi];
            float* dst = ws + WS_QP + (size_t)n * (NH * PQ * 3) + pi * 3;
            dst[0] = R[0] * x + R[1] * y + R[2] * zc + T[0];
            dst[1] = R[3] * x + R[4] * y + R[5] * zc + T[1];
            dst[2] = R[6] * x + R[7] * y + R[8] * zc + T[2];
        } else {
            int p2 = pi - 48;
            float x = rkv[r][p2], y = rkv[r][144 + p2], zc = rkv[r][288 + p2];
            int h = p2 / 12, pp = p2 % 12;
            float fx = R[0] * x + R[1] * y + R[2] * zc + T[0];
            float fy = R[3] * x + R[4] * y + R[5] * zc + T[1];
            float fz = R[6] * x + R[7] * y + R[8] * zc + T[2];
            if (pp < 4) {   // k_pts -> transposed [h][p*3+c][k]
                size_t b = WS_KPT + (size_t)(h * 12 + pp * 3) * N_RES + n;
                ws[b] = fx; ws[b + N_RES] = fy; ws[b + 2 * N_RES] = fz;
                atomicAdd(&kpsq_s[r][h], fx * fx + fy * fy + fz * fz);
            } else {
                float* dst = ws + WS_VP + (size_t)n * (NH * PV * 3) + (h * PV + pp - 4) * 3;
                dst[0] = fx; dst[1] = fy; dst[2] = fz;
            }
        }
    }
    __syncthreads();
    if (t < 96) ws[WS_KPSQ + (size_t)(n0 + t / 12) * NH + t % 12] = kpsq_s[t / 12][t % 12];
}

// ---------------- kernel 2: logit base = mask + sqrt(1/3)(z@Wb+bb) - 0.5hw*|kp|^2 ----------------
// coalesced stream over z; Wb/bb/hweights via uniform (SGPR) loads; fp16 output [q][h][k]
__global__ __launch_bounds__(256) void k_bias(
    const float* __restrict__ zg, const float* __restrict__ mask,
    const float* __restrict__ Wb, const float* __restrict__ bb,
    const float* __restrict__ hweights, float* __restrict__ ws)
{
    const int t = threadIdx.x;
    const int q = blockIdx.x / 3;
    const int k = (blockIdx.x % 3) * 256 + t;

    float acc[NH];
    #pragma unroll
    for (int h = 0; h < NH; h++) acc[h] = 0.f;
    const float* zr = zg + ((size_t)q * N_RES + k) * DP;
    for (int c4 = 0; c4 < 32; c4++) {
        float4 z4 = *(const float4*)(zr + c4 * 4);
        #pragma unroll
        for (int h = 0; h < NH; h++) {
            acc[h] += z4.x * Wb[(c4 * 4 + 0) * NH + h]
                    + z4.y * Wb[(c4 * 4 + 1) * NH + h]
                    + z4.z * Wb[(c4 * 4 + 2) * NH + h]
                    + z4.w * Wb[(c4 * 4 + 3) * NH + h];
        }
    }
    float mv = mask[(size_t)q * N_RES + k];
    const float* kps = ws + WS_KPSQ + (size_t)k * NH;
    __half* base = (__half*)(ws + WS_BASE);
    #pragma unroll
    for (int h = 0; h < NH; h++) {
        float hwv = log1pf(expf(hweights[h])) * 0.1360827635f;
        float v = mv + (acc[h] + bb[h]) * 0.5773502692f - 0.5f * hwv * kps[h];
        base[((size_t)q * NH + h) * N_RES + k] = __float2half(v);
    }
}

// ---------------- kernel 3: fused IPA attention ----------------
// grid (q, head-half): 1536 blocks, 128 thr = 2 waves, 3 heads/wave.
// No z LDS, no staging, NO barriers in the main loop. All logit operands
// transposed (coalesced); o_pair reads z direct from global (float2).
__global__ __launch_bounds__(128) void k_attn(
    const float* __restrict__ zg,
    const float* __restrict__ rot, const float* __restrict__ trans,
    const float* __restrict__ hweights,
    float* __restrict__ ws)
{
    __shared__ float p_s[7][68];
    __shared__ float qcat_s[6][28];   // [local head][0:16)=q*s1, [16:28)=qp*hw
    __shared__ float opts_s[6 * 24];
    __shared__ float r_s[8], inv_s[8];
    __shared__ float rot_s[9], trans_s[3];

    const int t = threadIdx.x;
    const int lane = t & 63;
    const int w = t >> 6;            // wave 0/1
    const int q  = blockIdx.x >> 1;
    const int hb = blockIdx.x & 1;   // head-half: global heads hb*6 .. hb*6+5
    const int hw0 = hb * 6;
    const int h0 = w * 3;            // wave's local head base

    // setup
    for (int i = t; i < 96; i += 128) {     // q part
        int hl = i >> 4, d = i & 15;
        qcat_s[hl][d] = ws[WS_Q + (size_t)q * HC + (hw0 + hl) * 16 + d] * 0.1443375673f;
    }
    for (int i = t; i < 72; i += 128) {     // qp part (pre-scaled by hw)
        int hl = i / 12, c = i % 12;
        float hwv = log1pf(expf(hweights[hw0 + hl])) * 0.1360827635f;
        qcat_s[hl][16 + c] = ws[WS_QP + (size_t)q * (NH * PQ * 3) + (hw0 + hl) * 12 + c] * hwv;
    }
    if (t < 9) rot_s[t] = rot[q * 9 + t];
    if (t < 3) trans_s[t] = trans[q * 3 + t];
    __syncthreads();

    float m_run[3], ssum[3], acc_z[3][2];
    #pragma unroll
    for (int hl = 0; hl < 3; hl++) {
        m_run[hl] = -1e30f; ssum[hl] = 0.f;
        acc_z[hl][0] = 0.f; acc_z[hl][1] = 0.f;
    }
    float acc_o = 0.f, acc_p0 = 0.f, acc_p1 = 0.f;

    const bool act_o = (lane < 48);
    const int h_o = h0 + (lane >> 4);        // valid when act_o
    const int h_pA = h0 + lane / 24;
    const bool act_p1 = (lane < 8);

    const __half* base = (const __half*)(ws + WS_BASE) + ((size_t)q * NH + hw0 + h0) * N_RES;
    const float* zq = zg + (size_t)q * N_RES * DP;

    for (int kb = 0; kb < N_RES; kb += BK) {
        const int kk = kb + lane;
        // ---- logits: base + dot16(q,K^T) + dot12(hw*qp, KP^T), all coalesced ----
        float logit[3];
        #pragma unroll
        for (int hl = 0; hl < 3; hl++) {
            int gh = hw0 + h0 + hl;
            float dot = __half2float(base[(size_t)hl * N_RES + kk]);
            const float* kt = ws + WS_KT + (size_t)(gh * DH) * N_RES + kk;
            #pragma unroll
            for (int d = 0; d < 16; d++)
                dot += qcat_s[h0 + hl][d] * kt[(size_t)d * N_RES];
            const float* kpt = ws + WS_KPT + (size_t)(gh * 12) * N_RES + kk;
            #pragma unroll
            for (int c = 0; c < 12; c++)
                dot += qcat_s[h0 + hl][16 + c] * kpt[(size_t)c * N_RES];
            logit[hl] = dot;
        }

        // ---- online softmax (wave-local) ----
        float rloc[3];
        #pragma unroll
        for (int hl = 0; hl < 3; hl++) {
            float lm = logit[hl];
            #pragma unroll
            for (int off = 32; off; off >>= 1) lm = fmaxf(lm, __shfl_xor(lm, off));
            float m_new = fmaxf(m_run[hl], lm);
            float rr = __expf(m_run[hl] - m_new);
            float p = __expf(logit[hl] - m_new);
            ssum[hl] = ssum[hl] * rr + p;
            p_s[h0 + hl][lane] = p;
            if (lane == 0) r_s[h0 + hl] = rr;
            rloc[hl] = rr;
            m_run[hl] = m_new;
        }

        // ---- o_pair: z direct from global, float2 per lane (cols 2*lane, 2*lane+1) ----
        #pragma unroll
        for (int hl = 0; hl < 3; hl++) { acc_z[hl][0] *= rloc[hl]; acc_z[hl][1] *= rloc[hl]; }
        #pragma unroll 4
        for (int j = 0; j < BK; j++) {
            float2 zz = *(const float2*)(zq + (size_t)(kb + j) * DP + 2 * lane);
            #pragma unroll
            for (int hl = 0; hl < 3; hl++) {
                float pv = p_s[h0 + hl][j];
                acc_z[hl][0] += pv * zz.x;
                acc_z[hl][1] += pv * zz.y;
            }
        }

        // ---- o from V ----
        if (act_o) {
            acc_o *= r_s[h_o];
            const float* vb = ws + WS_V + (size_t)kb * HC + hb * 96 + w * 48 + lane;
            #pragma unroll 4
            for (int j = 0; j < BK; j++)
                acc_o += p_s[h_o][j] * vb[(size_t)j * HC];
        }
        // ---- o_pts from VP (global frame) ----
        {
            acc_p0 *= r_s[h_pA];
            if (act_p1) acc_p1 *= r_s[h0 + 2];
            const float* vpb = ws + WS_VP + (size_t)kb * (NH * PV * 3) + hb * 144 + w * 72;
            #pragma unroll 4
            for (int j = 0; j < BK; j++) {
                const float* vr = vpb + (size_t)j * (NH * PV * 3);
                acc_p0 += p_s[h_pA][j] * vr[lane];
                if (act_p1) acc_p1 += p_s[h0 + 2][j] * vr[64 + lane];
            }
        }
    }

    // ---- denominators ----
    float inv[3];
    #pragma unroll
    for (int hl = 0; hl < 3; hl++) {
        float sv = ssum[hl];
        #pragma unroll
        for (int off = 32; off; off >>= 1) sv += __shfl_xor(sv, off);
        inv[hl] = 1.f / sv;
        if (lane == 0) inv_s[h0 + hl] = inv[hl];
    }

    float* cat = ws + WS_CAT + (size_t)q * CATD;
    if (act_o) cat[hb * 96 + w * 48 + lane] = acc_o * inv_s[h_o];
    opts_s[w * 72 + lane] = acc_p0 * inv_s[h_pA];
    if (act_p1) opts_s[w * 72 + 64 + lane] = acc_p1 * inv_s[h0 + 2];
    #pragma unroll
    for (int hl = 0; hl < 3; hl++) {
        int gh = hw0 + h0 + hl;
        cat[576 + gh * 128 + 2 * lane]     = acc_z[hl][0] * inv[hl];
        cat[576 + gh * 128 + 2 * lane + 1] = acc_z[hl][1] * inv[hl];
    }
    __syncthreads();   // opts_s crosses waves

    // inverse frame + norm: t<48 -> (local head, point)
    if (t < 48) {
        int ghl = t >> 3, p = t & 7;
        float gx = opts_s[ghl * 24 + p * 3 + 0] - trans_s[0];
        float gy = opts_s[ghl * 24 + p * 3 + 1] - trans_s[1];
        float gz = opts_s[ghl * 24 + p * 3 + 2] - trans_s[2];
        float lx = rot_s[0] * gx + rot_s[3] * gy + rot_s[6] * gz;
        float ly = rot_s[1] * gx + rot_s[4] * gy + rot_s[7] * gz;
        float lz = rot_s[2] * gx + rot_s[5] * gy + rot_s[8] * gz;
        cat[192 + hb * 48 + t] = lx;
        cat[288 + hb * 48 + t] = ly;
        cat[384 + hb * 48 + t] = lz;
        cat[480 + hb * 48 + t] = sqrtf(lx * lx + ly * ly + lz * lz + 1e-8f);
    }
}

// ---------------- kernel 4: cat @ Wout + bout ----------------
__global__ __launch_bounds__(384) void k_out(
    const float* __restrict__ ws, const float* __restrict__ Wout,
    const float* __restrict__ bout, float* __restrict__ out)
{
    __shared__ float cat_s[8][192];
    const int t = threadIdx.x;
    const int n0 = blockIdx.x * 8;
    float acc[8];
    #pragma unroll
    for (int r = 0; r < 8; r++) acc[r] = 0.f;
    for (int c0 = 0; c0 < CATD; c0 += 192) {
        __syncthreads();
        for (int idx = t; idx < 8 * 192; idx += 384)
            cat_s[idx / 192][idx % 192] =
                ws[WS_CAT + (size_t)(n0 + idx / 192) * CATD + c0 + idx % 192];
        __syncthreads();
        for (int i = 0; i < 192; i++) {
            float wv = Wout[(size_t)(c0 + i) * DS + t];
            #pragma unroll
            for (int r = 0; r < 8; r++) acc[r] += cat_s[r][i] * wv;
        }
    }
    float b = bout[t];
    #pragma unroll
    for (int r = 0; r < 8; r++) out[(size_t)(n0 + r) * DS + t] = acc[r] + b;
}

extern "C" void kernel_launch(void* const* d_in, const int* in_sizes, int n_in,
                              void* d_out, int out_size, void* d_ws, size_t ws_size,
                              hipStream_t stream)
{
    const float* s     = (const float*)d_in[0];
    const float* z     = (const float*)d_in[1];
    const float* mask  = (const float*)d_in[2];
    const float* rot   = (const float*)d_in[3];
    const float* trans = (const float*)d_in[4];
    const float* Wq    = (const float*)d_in[5];
    const float* bq    = (const float*)d_in[6];
    const float* Wkv   = (const float*)d_in[7];
    const float* bkv   = (const float*)d_in[8];
    const float* Wqp   = (const float*)d_in[9];
    const float* bqp   = (const float*)d_in[10];
    const float* Wkvp  = (const float*)d_in[11];
    const float* bkvp  = (const float*)d_in[12];
    const float* Wb    = (const float*)d_in[13];
    const float* bb    = (const float*)d_in[14];
    const float* hwt   = (const float*)d_in[15];
    const float* Wout  = (const float*)d_in[16];
    const float* bout  = (const float*)d_in[17];
    float* ws  = (float*)d_ws;
    float* out = (float*)d_out;

    hipLaunchKernelGGL(k_proj, dim3(96), dim3(256), 0, stream,
                       s, rot, trans, Wq, bq, Wkv, bkv, Wqp, bqp, Wkvp, bkvp, ws);
    hipLaunchKernelGGL(k_bias, dim3(2304), dim3(256), 0, stream,
                       z, mask, Wb, bb, hwt, ws);
    hipLaunchKernelGGL(k_attn, dim3(1536), dim3(128), 0, stream,
                       z, rot, trans, hwt, ws);
    hipLaunchKernelGGL(k_out, dim3(96), dim3(384), 0, stream,
                       ws, Wout, bout, out);
}

// Round 7
// 1145.843 us; speedup vs baseline: 2.6946x; 1.2293x over previous
//
#include <hip/hip_runtime.h>
#include <math.h>

#define N_RES 768
#define DS 384
#define DP 128
#define DH 16
#define NH 12
#define PQ 4
#define PV 8
#define HC (NH*DH)              // 192
#define CATD (NH*(DP+DH+PV*4))  // 2112
#define NSPLIT 4
#define KRANGE (N_RES/NSPLIT)   // 192
#define BK 32
#define ZP 132                  // padded z row; near-free banks (R1-measured)
#define PSTRIDE 2048            // per-(q,ks) partial: m12|s12|o192|opts288|opair1536

// ws float offsets
#define WS_Q    0                               // [768][192]
#define WS_KT   (WS_Q    + N_RES*HC)            // [12*16][768]
#define WS_V    (WS_KT   + NH*DH*N_RES)         // [768][192]
#define WS_QP   (WS_V    + N_RES*HC)            // [768][144]
#define WS_KPT  (WS_QP   + N_RES*NH*PQ*3)       // [12*12][768]
#define WS_VP   (WS_KPT  + NH*PQ*3*N_RES)       // [768][288]
#define WS_KPSQ (WS_VP   + N_RES*NH*PV*3)       // [12][768]
#define WS_WBT  (WS_KPSQ + NH*N_RES)            // [12][128]
#define WS_PART (WS_WBT  + NH*DP)               // [768*4][2048]
#define WS_CAT  (WS_PART + N_RES*NSPLIT*PSTRIDE)// [768][2112]

// ---------------- kernel 1: input projections + frame apply ----------------
__global__ __launch_bounds__(256) void k_proj(
    const float* __restrict__ s, const float* __restrict__ rot,
    const float* __restrict__ trans,
    const float* __restrict__ Wq, const float* __restrict__ bq,
    const float* __restrict__ Wkv, const float* __restrict__ bkv,
    const float* __restrict__ Wqp, const float* __restrict__ bqp,
    const float* __restrict__ Wkvp, const float* __restrict__ bkvp,
    const float* __restrict__ Wb,
    float* __restrict__ ws)
{
    __shared__ float s_s[8][DS];
    __shared__ float rq[8][NH*PQ*3];
    __shared__ float rkv[8][NH*(PQ+PV)*3];
    __shared__ float kpsq_s[8][NH];
    const int t = threadIdx.x;
    const int n0 = blockIdx.x * 8;

    for (int idx = t; idx < 8 * DS; idx += 256)
        s_s[idx / DS][idx % DS] = s[(n0 + idx / DS) * DS + idx % DS];
    if (t < 96) kpsq_s[t / 12][t % 12] = 0.f;
    if (blockIdx.x == 0) {      // WbT [h][c] for k_attn's L1-broadcast reads
        for (int i = t; i < DP * NH; i += 256)
            ws[WS_WBT + (i % NH) * DP + i / NH] = Wb[i];
    }
    __syncthreads();

    // 1152 output columns: [Wq 192 | Wkv 384 | Wqp 144 | Wkvp 432]
    for (int j = t; j < 1152; j += 256) {
        const float* W; int col, nc; float bias;
        if (j < 192)      { W = Wq;   col = j;       nc = 192; bias = bq[col]; }
        else if (j < 576) { W = Wkv;  col = j - 192; nc = 384; bias = bkv[col]; }
        else if (j < 720) { W = Wqp;  col = j - 576; nc = 144; bias = bqp[col]; }
        else              { W = Wkvp; col = j - 720; nc = 432; bias = bkvp[col]; }
        float acc[8];
        #pragma unroll
        for (int r = 0; r < 8; r++) acc[r] = bias;
        for (int i = 0; i < DS; i++) {
            float w = W[i * nc + col];
            #pragma unroll
            for (int r = 0; r < 8; r++) acc[r] += s_s[r][i] * w;
        }
        if (j < 192) {
            #pragma unroll
            for (int r = 0; r < 8; r++) ws[WS_Q + (size_t)(n0 + r) * HC + j] = acc[r];
        } else if (j < 576) {
            int jj = j - 192, h = jj / 32, dd = jj % 32;
            if (dd < 16) {  // K -> transposed [h*16+d][k]
                #pragma unroll
                for (int r = 0; r < 8; r++)
                    ws[WS_KT + (size_t)(h * DH + dd) * N_RES + (n0 + r)] = acc[r];
            } else {
                #pragma unroll
                for (int r = 0; r < 8; r++)
                    ws[WS_V + (size_t)(n0 + r) * HC + h * 16 + dd - 16] = acc[r];
            }
        } else if (j < 720) {
            #pragma unroll
            for (int r = 0; r < 8; r++) rq[r][j - 576] = acc[r];
        } else {
            #pragma unroll
            for (int r = 0; r < 8; r++) rkv[r][j - 720] = acc[r];
        }
    }
    __syncthreads();

    // frame apply: 8 rows * (48 qp + 144 kvp) points
    for (int idx = t; idx < 8 * 192; idx += 256) {
        int r = idx / 192, pi = idx % 192;
        int n = n0 + r;
        const float* R = rot + n * 9;
        const float* T = trans + n * 3;
        if (pi < 48) {
            float x = rq[r][pi], y = rq[r][48 + pi], zc = rq[r][96 + pi];
            float* dst = ws + WS_QP + (size_t)n * (NH * PQ * 3) + pi * 3;
            dst[0] = R[0] * x + R[1] * y + R[2] * zc + T[0];
            dst[1] = R[3] * x + R[4] * y + R[5] * zc + T[1];
            dst[2] = R[6] * x + R[7] * y + R[8] * zc + T[2];
        } else {
            int p2 = pi - 48;
            float x = rkv[r][p2], y = rkv[r][144 + p2], zc = rkv[r][288 + p2];
            int h = p2 / 12, pp = p2 % 12;
            float fx = R[0] * x + R[1] * y + R[2] * zc + T[0];
            float fy = R[3] * x + R[4] * y + R[5] * zc + T[1];
            float fz = R[6] * x + R[7] * y + R[8] * zc + T[2];
            if (pp < 4) {   // k_pts -> transposed [h*12 + p*3+c][k]
                size_t b = WS_KPT + (size_t)(h * 12 + pp * 3) * N_RES + n;
                ws[b] = fx; ws[b + N_RES] = fy; ws[b + 2 * N_RES] = fz;
                atomicAdd(&kpsq_s[r][h], fx * fx + fy * fy + fz * fz);
            } else {
                float* dst = ws + WS_VP + (size_t)n * (NH * PV * 3) + (h * PV + pp - 4) * 3;
                dst[0] = fx; dst[1] = fy; dst[2] = fz;
            }
        }
    }
    __syncthreads();
    if (t < 96)   // kpsq transposed [h][k] for coalesced k_attn reads
        ws[WS_KPSQ + (size_t)(t % 12) * N_RES + (n0 + t / 12)] = kpsq_s[t / 12][t % 12];
}

// ---------------- kernel 2: split-K fused IPA attention ----------------
// grid (q, ksplit) = 3072 blocks, 128 thr = 2 waves; wave w owns heads 6w..6w+5.
// Online softmax over 192-k slice; z staged in LDS (pad-132); unnormalized
// partials (m, ssum, o, opts, opair) written to ws for k_merge.
__global__ __launch_bounds__(128) void k_attn(
    const float* __restrict__ zg, const float* __restrict__ mask,
    const float* __restrict__ bb, const float* __restrict__ hweights,
    float* __restrict__ ws)
{
    __shared__ float z_s[BK * ZP];      // 16.9 KB
    __shared__ float p_s[NH][BK];
    __shared__ float q_s[HC];
    __shared__ float qph_s[NH * 12];
    __shared__ float r_s[NH];

    const int t = threadIdx.x;
    const int lane = t & 63;
    const int w = t >> 6;
    const int h0 = 6 * w;
    const int q  = blockIdx.x >> 2;
    const int ks = blockIdx.x & 3;
    const int kbase = ks * KRANGE;
    const float* zq = zg + ((size_t)q * N_RES + kbase) * DP;
    const float* wbt = ws + WS_WBT;

    for (int i = t; i < HC; i += 128)
        q_s[i] = ws[WS_Q + (size_t)q * HC + i] * 0.1443375673f;     // sqrt(1/48)
    for (int i = t; i < 144; i += 128) {
        float hwv = log1pf(expf(hweights[i / 12])) * 0.1360827635f; // softplus*sqrt(1/54)
        qph_s[i] = ws[WS_QP + (size_t)q * 144 + i] * hwv;
    }

    float hw[6], bbv[6];
    #pragma unroll
    for (int hl = 0; hl < 6; hl++) {
        hw[hl] = log1pf(expf(hweights[h0 + hl])) * 0.1360827635f;
        bbv[hl] = bb[h0 + hl];
    }

    float m_run[6], ssum[6], acc_z[6][2];
    #pragma unroll
    for (int hl = 0; hl < 6; hl++) {
        m_run[hl] = -1e30f; ssum[hl] = 0.f;
        acc_z[hl][0] = 0.f; acc_z[hl][1] = 0.f;
    }
    float acc_o0 = 0.f, acc_o1 = 0.f;
    float acc_p0 = 0.f, acc_p1 = 0.f, acc_p2 = 0.f;

    const int kl = lane & 31;          // local k within tile (halves duplicate)
    const int half = lane >> 5;
    const int h_o0 = h0 + (lane >> 4);
    const int h_o1 = h0 + 4 + (lane >> 4);     // lane<32
    const int h_p0 = h0 + lane / 24;
    const int h_p1 = h0 + (lane + 64) / 24;
    const int h_p2 = h0 + (lane + 128) / 24;   // lane<16

    for (int kb = 0; kb < KRANGE; kb += BK) {
        __syncthreads();   // prev tile's z_s consumers done
        {
            const float4* src = (const float4*)(zq + (size_t)kb * DP);
            #pragma unroll
            for (int i = 0; i < 8; i++) {
                int idx = i * 128 + t;
                float4 v = src[idx];
                *(float4*)&z_s[(idx >> 5) * ZP + (idx & 31) * 4] = v;
            }
        }
        __syncthreads();   // tile staged

        const int kk = kbase + kb + kl;
        // ---- bias dot: each half-wave does 64 cols, then combine ----
        float bacc[6] = {0.f, 0.f, 0.f, 0.f, 0.f, 0.f};
        for (int c4 = 0; c4 < 16; c4++) {
            int chunk = half * 16 + c4;
            float4 z4 = *(const float4*)&z_s[kl * ZP + chunk * 4];
            #pragma unroll
            for (int hl = 0; hl < 6; hl++) {
                float4 w4 = *(const float4*)&wbt[(h0 + hl) * DP + chunk * 4];
                bacc[hl] += z4.x * w4.x + z4.y * w4.y + z4.z * w4.z + z4.w * w4.w;
            }
        }
        #pragma unroll
        for (int hl = 0; hl < 6; hl++) bacc[hl] += __shfl_xor(bacc[hl], 32);

        // ---- logits (coalesced transposed reads) ----
        float mval = mask[(size_t)q * N_RES + kk];
        float logit[6];
        #pragma unroll
        for (int hl = 0; hl < 6; hl++) {
            int gh = h0 + hl;
            float dot = (bacc[hl] + bbv[hl]) * 0.5773502692f + mval
                        - 0.5f * hw[hl] * ws[WS_KPSQ + (size_t)gh * N_RES + kk];
            const float* kt = ws + WS_KT + (size_t)(gh * DH) * N_RES + kk;
            #pragma unroll
            for (int d = 0; d < 16; d++)
                dot += q_s[gh * 16 + d] * kt[(size_t)d * N_RES];
            const float* kpt = ws + WS_KPT + (size_t)(gh * 12) * N_RES + kk;
            #pragma unroll
            for (int c = 0; c < 12; c++)
                dot += qph_s[gh * 12 + c] * kpt[(size_t)c * N_RES];
            logit[hl] = dot;
        }

        // ---- online softmax over 32-lane group (halves duplicated) ----
        float rloc[6];
        #pragma unroll
        for (int hl = 0; hl < 6; hl++) {
            float lm = logit[hl];
            #pragma unroll
            for (int off = 16; off; off >>= 1) lm = fmaxf(lm, __shfl_xor(lm, off));
            float m_new = fmaxf(m_run[hl], lm);
            float rr = __expf(m_run[hl] - m_new);
            float p = __expf(logit[hl] - m_new);
            ssum[hl] = ssum[hl] * rr + p;
            p_s[h0 + hl][kl] = p;
            if (lane == 0) r_s[h0 + hl] = rr;
            rloc[hl] = rr;
            m_run[hl] = m_new;
        }
        // no barrier: p_s/r_s wave-local, in-order LDS

        // ---- o_pair from staged z (lane owns cols lane, 64+lane) ----
        #pragma unroll
        for (int hl = 0; hl < 6; hl++) { acc_z[hl][0] *= rloc[hl]; acc_z[hl][1] *= rloc[hl]; }
        #pragma unroll 4
        for (int j = 0; j < BK; j++) {
            float z0 = z_s[j * ZP + lane];
            float z1 = z_s[j * ZP + 64 + lane];
            #pragma unroll
            for (int hl = 0; hl < 6; hl++) {
                float pv = p_s[h0 + hl][j];
                acc_z[hl][0] += pv * z0;
                acc_z[hl][1] += pv * z1;
            }
        }

        // ---- o from V (coalesced 256B rows) ----
        {
            acc_o0 *= r_s[h_o0];
            if (lane < 32) acc_o1 *= r_s[h_o1];
            const float* vbase = ws + WS_V + (size_t)(kbase + kb) * HC + w * 96 + lane;
            #pragma unroll 4
            for (int j = 0; j < BK; j++) {
                acc_o0 += p_s[h_o0][j] * vbase[(size_t)j * HC];
                if (lane < 32) acc_o1 += p_s[h_o1][j] * vbase[(size_t)j * HC + 64];
            }
        }
        // ---- o_pts from VP (global frame) ----
        {
            acc_p0 *= r_s[h_p0];
            acc_p1 *= r_s[h_p1];
            if (lane < 16) acc_p2 *= r_s[h_p2];
            const float* vpb = ws + WS_VP + (size_t)(kbase + kb) * 288 + w * 144;
            #pragma unroll 4
            for (int j = 0; j < BK; j++) {
                const float* vr = vpb + (size_t)j * 288;
                acc_p0 += p_s[h_p0][j] * vr[lane];
                acc_p1 += p_s[h_p1][j] * vr[64 + lane];
                if (lane < 16) acc_p2 += p_s[h_p2][j] * vr[128 + lane];
            }
        }
    }

    // ---- write unnormalized partials ----
    float* part = ws + WS_PART + (size_t)blockIdx.x * PSTRIDE;
    #pragma unroll
    for (int hl = 0; hl < 6; hl++) {   // ssum: sum within 32-group (halves dup)
        float sv = ssum[hl];
        #pragma unroll
        for (int off = 16; off; off >>= 1) sv += __shfl_xor(sv, off);
        ssum[hl] = sv;
    }
    if (lane == 0) {
        #pragma unroll
        for (int hl = 0; hl < 6; hl++) {
            part[h0 + hl] = m_run[hl];
            part[12 + h0 + hl] = ssum[hl];
        }
    }
    part[24 + w * 96 + lane] = acc_o0;
    if (lane < 32) part[24 + w * 96 + 64 + lane] = acc_o1;
    part[216 + w * 144 + lane] = acc_p0;
    part[216 + w * 144 + 64 + lane] = acc_p1;
    if (lane < 16) part[216 + w * 144 + 128 + lane] = acc_p2;
    #pragma unroll
    for (int hl = 0; hl < 6; hl++) {
        part[504 + (h0 + hl) * 128 + lane] = acc_z[hl][0];
        part[504 + (h0 + hl) * 128 + 64 + lane] = acc_z[hl][1];
    }
}

// ---------------- kernel 3: merge partials + epilogue ----------------
__global__ __launch_bounds__(256) void k_merge(
    const float* __restrict__ rot, const float* __restrict__ trans,
    float* __restrict__ ws)
{
    __shared__ float w_s[NSPLIT][NH];
    __shared__ float opts_s[288];
    __shared__ float rot_s[9], trans_s[3];
    const int t = threadIdx.x;
    const int q = blockIdx.x;
    const float* P0 = ws + WS_PART + (size_t)q * NSPLIT * PSTRIDE;

    if (t < NH) {
        float m0 = P0[t], m1 = P0[PSTRIDE + t], m2 = P0[2 * PSTRIDE + t], m3 = P0[3 * PSTRIDE + t];
        float M = fmaxf(fmaxf(m0, m1), fmaxf(m2, m3));
        float e0 = __expf(m0 - M), e1 = __expf(m1 - M), e2 = __expf(m2 - M), e3 = __expf(m3 - M);
        float denom = e0 * P0[12 + t] + e1 * P0[PSTRIDE + 12 + t]
                    + e2 * P0[2 * PSTRIDE + 12 + t] + e3 * P0[3 * PSTRIDE + 12 + t];
        float inv = 1.f / denom;
        w_s[0][t] = e0 * inv; w_s[1][t] = e1 * inv;
        w_s[2][t] = e2 * inv; w_s[3][t] = e3 * inv;
    }
    if (t < 9) rot_s[t] = rot[q * 9 + t];
    if (t < 3) trans_s[t] = trans[q * 3 + t];
    __syncthreads();

    float* cat = ws + WS_CAT + (size_t)q * CATD;
    for (int e = t; e < 2016; e += 256) {
        int h, po;
        if (e < 192)      { h = e >> 4;          po = 24 + e; }
        else if (e < 480) { h = (e - 192) / 24;  po = 216 + (e - 192); }
        else              { h = (e - 480) >> 7;  po = 504 + (e - 480); }
        float val = w_s[0][h] * P0[po] + w_s[1][h] * P0[PSTRIDE + po]
                  + w_s[2][h] * P0[2 * PSTRIDE + po] + w_s[3][h] * P0[3 * PSTRIDE + po];
        if (e < 192)      cat[e] = val;
        else if (e < 480) opts_s[e - 192] = val;
        else              cat[576 + (e - 480)] = val;
    }
    __syncthreads();

    if (t < 96) {   // inverse frame + norm
        int gh = t >> 3, p = t & 7;
        float gx = opts_s[gh * 24 + p * 3 + 0] - trans_s[0];
        float gy = opts_s[gh * 24 + p * 3 + 1] - trans_s[1];
        float gz = opts_s[gh * 24 + p * 3 + 2] - trans_s[2];
        float lx = rot_s[0] * gx + rot_s[3] * gy + rot_s[6] * gz;
        float ly = rot_s[1] * gx + rot_s[4] * gy + rot_s[7] * gz;
        float lz = rot_s[2] * gx + rot_s[5] * gy + rot_s[8] * gz;
        cat[192 + t] = lx;
        cat[288 + t] = ly;
        cat[384 + t] = lz;
        cat[480 + t] = sqrtf(lx * lx + ly * ly + lz * lz + 1e-8f);
    }
}

// ---------------- kernel 4: cat @ Wout + bout ----------------
__global__ __launch_bounds__(384) void k_out(
    const float* __restrict__ ws, const float* __restrict__ Wout,
    const float* __restrict__ bout, float* __restrict__ out)
{
    __shared__ float cat_s[4][192];
    const int t = threadIdx.x;
    const int n0 = blockIdx.x * 4;
    float acc[4];
    #pragma unroll
    for (int r = 0; r < 4; r++) acc[r] = 0.f;
    for (int c0 = 0; c0 < CATD; c0 += 192) {
        __syncthreads();
        for (int idx = t; idx < 4 * 192; idx += 384)
            cat_s[idx / 192][idx % 192] =
                ws[WS_CAT + (size_t)(n0 + idx / 192) * CATD + c0 + idx % 192];
        __syncthreads();
        for (int i = 0; i < 192; i++) {
            float wv = Wout[(size_t)(c0 + i) * DS + t];
            #pragma unroll
            for (int r = 0; r < 4; r++) acc[r] += cat_s[r][i] * wv;
        }
    }
    float b = bout[t];
    #pragma unroll
    for (int r = 0; r < 4; r++) out[(size_t)(n0 + r) * DS + t] = acc[r] + b;
}

extern "C" void kernel_launch(void* const* d_in, const int* in_sizes, int n_in,
                              void* d_out, int out_size, void* d_ws, size_t ws_size,
                              hipStream_t stream)
{
    const float* s     = (const float*)d_in[0];
    const float* z     = (const float*)d_in[1];
    const float* mask  = (const float*)d_in[2];
    const float* rot   = (const float*)d_in[3];
    const float* trans = (const float*)d_in[4];
    const float* Wq    = (const float*)d_in[5];
    const float* bq    = (const float*)d_in[6];
    const float* Wkv   = (const float*)d_in[7];
    const float* bkv   = (const float*)d_in[8];
    const float* Wqp   = (const float*)d_in[9];
    const float* bqp   = (const float*)d_in[10];
    const float* Wkvp  = (const float*)d_in[11];
    const float* bkvp  = (const float*)d_in[12];
    const float* Wb    = (const float*)d_in[13];
    const float* bb    = (const float*)d_in[14];
    const float* hwt   = (const float*)d_in[15];
    const float* Wout  = (const float*)d_in[16];
    const float* bout  = (const float*)d_in[17];
    float* ws  = (float*)d_ws;
    float* out = (float*)d_out;

    hipLaunchKernelGGL(k_proj, dim3(96), dim3(256), 0, stream,
                       s, rot, trans, Wq, bq, Wkv, bkv, Wqp, bqp, Wkvp, bkvp, Wb, ws);
    hipLaunchKernelGGL(k_attn, dim3(N_RES * NSPLIT), dim3(128), 0, stream,
                       z, mask, bb, hwt, ws);
    hipLaunchKernelGGL(k_merge, dim3(N_RES), dim3(256), 0, stream,
                       rot, trans, ws);
    hipLaunchKernelGGL(k_out, dim3(192), dim3(384), 0, stream,
                       ws, Wout, bout, out);
}